// Round 2
// 603.135 us; speedup vs baseline: 1.1319x; 1.1319x over previous
//
#include <hip/hip_runtime.h>
#include <math.h>

#define D 128
#define NG 1024          // graphs
#define NBLK 512         // blocks per work type (pos / neg / kl)

typedef __bf16 bf16x8 __attribute__((ext_vector_type(8)));
typedef float f32x4 __attribute__((ext_vector_type(4)));

#define MFMA __builtin_amdgcn_mfma_f32_16x16x32_bf16

// lgkm-only barrier: does NOT drain vmcnt, so prefetched global loads stay in
// flight across tile boundaries (the __syncthreads vmcnt(0) drain kills the
// pipeline). sched_barrier(0) pins ds ops / load issue on their side (rule #18).
__device__ __forceinline__ void bar_lds() {
    __builtin_amdgcn_sched_barrier(0);
    asm volatile("s_waitcnt lgkmcnt(0)" ::: "memory");
    __builtin_amdgcn_s_barrier();
    __builtin_amdgcn_sched_barrier(0);
}

// two f32 -> packed bf16 dword (RNE, compiler emits cvt_pk where possible)
__device__ __forceinline__ unsigned pk2(float a, float b) {
    union { __bf16 h[2]; unsigned u; } x;
    x.h[0] = (__bf16)a; x.h[1] = (__bf16)b;
    return x.u;
}

// BCE(sigmoid(z), ta) with torch -100 log clamps ==
//   ta*min(sp(-z),100) + (1-ta)*min(sp(z),100),  sp(z)=max(z,0)+log1p(exp(-|z|))
// (exact algebra on the same clamps; precise expf/log1pf used below)

// Wave-level segmented atomic accumulate; all 64 lanes converged.
__device__ __forceinline__ void seg_atomic(float* __restrict__ seg, int g, float v, bool valid) {
    float tv = valid ? v : 0.f;
    float s = tv;
#pragma unroll
    for (int o = 1; o < 64; o <<= 1) s += __shfl_xor(s, o, 64);
    unsigned long long vb = __ballot(valid);
    if (vb == 0ULL) return;
    int g0 = __shfl(g, __ffsll((unsigned long long)vb) - 1, 64);
    unsigned long long ub = __ballot((!valid) || (g == g0));
    const int lane = (int)(threadIdx.x & 63u);
    if (ub == ~0ULL) {
        if (lane == 0) atomicAdd(seg + g0, s);
    } else {
        if (valid) atomicAdd(seg + g, tv);
    }
}

__device__ __forceinline__ void wave_add(float* __restrict__ dst, float v) {
    float s = v;
#pragma unroll
    for (int o = 1; o < 64; o <<= 1) s += __shfl_xor(s, o, 64);
    if ((threadIdx.x & 63u) == 0) atomicAdd(dst, s);
}

// ---------------------------------------------------------------------------
// shared layout (floats): As 0..4096 | Hbf 4096..8448 (8704 shorts, stride 136)
// LoS 8448..16640 (We1-lo frags, 32 blk x 512 shorts) | W2f 16640..17664
// posP 17664..17920 | b1s 17920 | be1s 18048 | We2s 18176 | b2s 18304 | be2s 18312
#define SMEM_F 18320

// A-slot swizzle: logical (blk=mt*4+kt, q, m) -> physical m' = (m&8)|((m^g)&7),
// g = kt + 4*(q>>1). Writer's 8 same-edge lanes (ks=0..7) map g to all 8 values
// (Latin square) -> 8 distinct bank groups per write phase (was the 9M-conflict
// 8-way ds_write collision). Readers apply the same XOR via 4 per-lane offsets.

__device__ __forceinline__ void pos_body(float* smem, int brank,
    const float* __restrict__ x, const int* __restrict__ ei, const int* __restrict__ ebatch,
    const float* __restrict__ W1, const float* __restrict__ b1,
    const float* __restrict__ W2, const float* __restrict__ b2,
    const float* __restrict__ We1, const float* __restrict__ be1,
    const float* __restrict__ We2, const float* __restrict__ be2,
    const float* __restrict__ attr,
    float* __restrict__ posSum, float* __restrict__ posCnt, float* __restrict__ tot1,
    int E, int ntiles)
{
    unsigned short* As16 = (unsigned short*)smem;
    unsigned short* Hb   = (unsigned short*)(smem + 4096);
    unsigned short* LoS  = (unsigned short*)(smem + 8448);
    unsigned short* W2f  = (unsigned short*)(smem + 16640);
    float* posP = smem + 17664;
    float* b1s  = smem + 17920;
    float* be1s = smem + 18048;
    float* We2s = smem + 18176;
    float* b2s  = smem + 18304;
    float* be2s = smem + 18312;

    const int t   = (int)threadIdx.x;
    const int wv  = t >> 6;
    const int l   = t & 63;
    const int sub = l & 15;
    const int q   = l >> 4;

    bf16x8 Bh[2][4];   // wv<4: W1 cols; wv>=4: We1-hi cols

    // ---- one-time: Bh fragments via As staging (8 passes)
#pragma unroll
    for (int pass = 0; pass < 8; pass++) {
        const int mm = pass >> 2;      // 0: W1, 1: We1-hi
        const int kt = pass & 3;
        const float* Wsrc = mm ? We1 : W1;
        __syncthreads();
        {
            const int ct = t >> 6, ln = t & 63;
            const int n  = ct * 16 + (ln & 15);
            const int kb = kt * 32 + (ln >> 4) * 8;
            uint4 u;
            u.x = pk2(Wsrc[(kb + 0) * D + n], Wsrc[(kb + 1) * D + n]);
            u.y = pk2(Wsrc[(kb + 2) * D + n], Wsrc[(kb + 3) * D + n]);
            u.z = pk2(Wsrc[(kb + 4) * D + n], Wsrc[(kb + 5) * D + n]);
            u.w = pk2(Wsrc[(kb + 6) * D + n], Wsrc[(kb + 7) * D + n]);
            *(uint4*)(As16 + (ct * 64 + ln) * 8) = u;
        }
        __syncthreads();
        int ct0 = -1;
        if (mm == 0 && wv < 4)  ct0 = 2 * wv;
        if (mm == 1 && wv >= 4) ct0 = 2 * (wv - 4);
        if (ct0 >= 0) {
            Bh[0][kt] = *(const bf16x8*)(As16 + (ct0 * 64 + l) * 8);
            Bh[1][kt] = *(const bf16x8*)(As16 + ((ct0 + 1) * 64 + l) * 8);
        }
    }
    __syncthreads();
    // ---- one-time: We1-lo fragments -> LDS (frees ~32 regs vs register-resident)
    for (int idx = t; idx < 2048; idx += 512) {
        const int blk = idx >> 6, l2 = idx & 63;
        const int col = (blk >> 3) * 32 + ((blk >> 2) & 1) * 16 + (l2 & 15);
        const int k0  = (blk & 3) * 32 + (l2 >> 4) * 8;
        float f[8];
#pragma unroll
        for (int j = 0; j < 8; j++) {
            float v = We1[(k0 + j) * D + col];
            f[j] = v - (float)(__bf16)v;           // lo residual
        }
        uint4 u;
        u.x = pk2(f[0], f[1]); u.y = pk2(f[2], f[3]);
        u.z = pk2(f[4], f[5]); u.w = pk2(f[6], f[7]);
        *(uint4*)(LoS + idx * 8) = u;
    }
    // ---- one-time: W2 fragments -> LDS (cols 7..15 zero)
    if (t < 256) {
        const int l2 = t & 63;
        const int sb = l2 & 15;
        const int k0 = (t >> 6) * 32 + (l2 >> 4) * 8;
        uint4 u;
        if (sb < 7) {
            u.x = pk2(W2[(k0 + 0) * 7 + sb], W2[(k0 + 1) * 7 + sb]);
            u.y = pk2(W2[(k0 + 2) * 7 + sb], W2[(k0 + 3) * 7 + sb]);
            u.z = pk2(W2[(k0 + 4) * 7 + sb], W2[(k0 + 5) * 7 + sb]);
            u.w = pk2(W2[(k0 + 6) * 7 + sb], W2[(k0 + 7) * 7 + sb]);
        } else { u.x = u.y = u.z = u.w = 0u; }
        *(uint4*)(W2f + t * 8) = u;
    }
    if (t < 128) { b1s[t] = b1[t]; be1s[t] = be1[t]; We2s[t] = We2[t]; }
    if (t < 7) b2s[t] = b2[t];
    if (t == 7) be2s[0] = be2[0];
    __syncthreads();

    // swizzled reader offsets (per kt, lane-constant)
    int roff[4];
#pragma unroll
    for (int kt = 0; kt < 4; kt++) {
        const int g2 = kt + ((q >> 1) << 2);
        roff[kt] = (q * 16 + ((sub & 8) | ((sub ^ g2) & 7))) * 8;
    }
    // swizzled writer slot (lane-constant)
    const int e_  = t >> 3, ks_ = t & 7;
    const int gw  = (ks_ >> 1) | ((ks_ & 1) << 2);
    const int wsl = ((e_ >> 4) * 4 + (ks_ >> 1)) * 64
                  + ((ks_ & 1) * 2) * 16 + ((e_ & 8) | ((e_ ^ gw) & 7));
    unsigned short* wp = As16 + wsl * 8;
    const int k0_ = ks_ * 16;

    float lpAcc = 0.f;

    // ---- software pipeline prologue: ei 2-deep, x rows 1-deep
    int tile = brank;
    float4 rs0, rs1, rs2, rs3, rd0, rd1, rd2, rd3;
    int sN, dN;
    {
        const int Ei0 = tile * 64 + e_;
        const int ix  = Ei0 < E ? Ei0 : E - 1;
        const int s0 = ei[ix], d0 = ei[E + ix];
        const float4* ps = (const float4*)(x + (size_t)s0 * D + k0_);
        const float4* pd = (const float4*)(x + (size_t)d0 * D + k0_);
        rs0 = ps[0]; rs1 = ps[1]; rs2 = ps[2]; rs3 = ps[3];
        rd0 = pd[0]; rd1 = pd[1]; rd2 = pd[2]; rd3 = pd[3];
        const int t1  = tile + NBLK;
        int Ei1 = (t1 < ntiles) ? t1 * 64 + e_ : 0;
        Ei1 = Ei1 < E ? Ei1 : E - 1;               // clamp (E may not be /64)
        sN = ei[Ei1]; dN = ei[E + Ei1];
    }

    for (; tile < ntiles; tile += NBLK) {
        const int base = tile * 64;
        const int Ei = base + e_;
        const bool vE = (Ei < E);
        uint4 u0, u1;
        if (vE) {
            u0.x = pk2(fmaxf(rs0.x * rd0.x, 0.f), fmaxf(rs0.y * rd0.y, 0.f));
            u0.y = pk2(fmaxf(rs0.z * rd0.z, 0.f), fmaxf(rs0.w * rd0.w, 0.f));
            u0.z = pk2(fmaxf(rs1.x * rd1.x, 0.f), fmaxf(rs1.y * rd1.y, 0.f));
            u0.w = pk2(fmaxf(rs1.z * rd1.z, 0.f), fmaxf(rs1.w * rd1.w, 0.f));
            u1.x = pk2(fmaxf(rs2.x * rd2.x, 0.f), fmaxf(rs2.y * rd2.y, 0.f));
            u1.y = pk2(fmaxf(rs2.z * rd2.z, 0.f), fmaxf(rs2.w * rd2.w, 0.f));
            u1.z = pk2(fmaxf(rs3.x * rd3.x, 0.f), fmaxf(rs3.y * rd3.y, 0.f));
            u1.w = pk2(fmaxf(rs3.z * rd3.z, 0.f), fmaxf(rs3.w * rd3.w, 0.f));
        } else { u0.x = u0.y = u0.z = u0.w = 0u; u1 = u0; }
        *(uint4*)wp = u0;
        *(uint4*)(wp + 128) = u1;
        // issue next tile's x loads now (they fly across both barriers + MFMAs)
        const int t1 = tile + NBLK;
        if (t1 < ntiles) {
            const float4* ps = (const float4*)(x + (size_t)sN * D + k0_);
            const float4* pd = (const float4*)(x + (size_t)dN * D + k0_);
            rs0 = ps[0]; rs1 = ps[1]; rs2 = ps[2]; rs3 = ps[3];
            rd0 = pd[0]; rd1 = pd[1]; rd2 = pd[2]; rd3 = pd[3];
            const int t2 = t1 + NBLK;
            if (t2 < ntiles) {
                int Ei2 = t2 * 64 + e_;
                Ei2 = Ei2 < E ? Ei2 : E - 1;       // clamp
                sN = ei[Ei2]; dN = ei[E + Ei2];
            }
        }
        bar_lds();                      // barrier G (lgkm only)
        // ---- layer 1
#pragma unroll
        for (int mt = 0; mt < 4; mt++) {
            const int ab = mt * 2048;
            bf16x8 a0 = *(const bf16x8*)(As16 + ab +        roff[0]);
            bf16x8 a1 = *(const bf16x8*)(As16 + ab +  512 + roff[1]);
            bf16x8 a2 = *(const bf16x8*)(As16 + ab + 1024 + roff[2]);
            bf16x8 a3 = *(const bf16x8*)(As16 + ab + 1536 + roff[3]);
            if (wv < 4) {
#pragma unroll
                for (int ct = 0; ct < 2; ct++) {
                    f32x4 c = {0.f, 0.f, 0.f, 0.f};
                    c = MFMA(a0, Bh[ct][0], c, 0, 0, 0);
                    c = MFMA(a1, Bh[ct][1], c, 0, 0, 0);
                    c = MFMA(a2, Bh[ct][2], c, 0, 0, 0);
                    c = MFMA(a3, Bh[ct][3], c, 0, 0, 0);
                    const int jloc = wv * 32 + ct * 16 + sub;
                    const float bb = b1s[jloc];
#pragma unroll
                    for (int r = 0; r < 4; r++)
                        *(__bf16*)(Hb + (mt * 16 + q * 4 + r) * 136 + jloc) =
                            (__bf16)fmaxf(c[r] + bb, 0.f);
                }
            } else {
                const unsigned short* lob = LoS + ((wv - 4) << 12) + l * 8;
                float zp0 = 0.f, zp1 = 0.f, zp2 = 0.f, zp3 = 0.f;
#pragma unroll
                for (int ct = 0; ct < 2; ct++) {
                    bf16x8 lo0 = *(const bf16x8*)(lob + ct * 2048);
                    bf16x8 lo1 = *(const bf16x8*)(lob + ct * 2048 + 512);
                    bf16x8 lo2 = *(const bf16x8*)(lob + ct * 2048 + 1024);
                    bf16x8 lo3 = *(const bf16x8*)(lob + ct * 2048 + 1536);
                    f32x4 c = {0.f, 0.f, 0.f, 0.f};
                    c = MFMA(a0, Bh[ct][0], c, 0, 0, 0);
                    c = MFMA(a1, Bh[ct][1], c, 0, 0, 0);
                    c = MFMA(a2, Bh[ct][2], c, 0, 0, 0);
                    c = MFMA(a3, Bh[ct][3], c, 0, 0, 0);
                    c = MFMA(a0, lo0, c, 0, 0, 0);
                    c = MFMA(a1, lo1, c, 0, 0, 0);
                    c = MFMA(a2, lo2, c, 0, 0, 0);
                    c = MFMA(a3, lo3, c, 0, 0, 0);
                    const int jloc = ((wv & 3) << 5) + ct * 16 + sub;
                    const float bb = be1s[jloc], ww = We2s[jloc];
                    zp0 += fmaxf(c[0] + bb, 0.f) * ww;
                    zp1 += fmaxf(c[1] + bb, 0.f) * ww;
                    zp2 += fmaxf(c[2] + bb, 0.f) * ww;
                    zp3 += fmaxf(c[3] + bb, 0.f) * ww;
                }
#pragma unroll
                for (int o = 1; o < 16; o <<= 1) {
                    zp0 += __shfl_xor(zp0, o, 64);
                    zp1 += __shfl_xor(zp1, o, 64);
                    zp2 += __shfl_xor(zp2, o, 64);
                    zp3 += __shfl_xor(zp3, o, 64);
                }
                if (sub < 4) {
                    float vv = (sub == 0) ? zp0 : (sub == 1) ? zp1 : (sub == 2) ? zp2 : zp3;
                    posP[((wv - 4) << 6) + (mt << 4) + (q << 2) + sub] = vv;
                }
            }
        }
        bar_lds();                      // barrier M
        // ---- layer 2 (waves 0-3), unified softplus BCE (no sub<7/==7 divergence)
        if (wv < 4) {
            f32x4 cS = {0.f, 0.f, 0.f, 0.f};
#pragma unroll
            for (int jt = 0; jt < 4; jt++) {
                bf16x8 hf  = *(const bf16x8*)(Hb + (wv * 16 + sub) * 136 + jt * 32 + q * 8);
                bf16x8 w2v = *(const bf16x8*)(W2f + jt * 512 + l * 8);
                cS = MFMA(hf, w2v, cS, 0, 0, 0);
            }
            float bceP[4], lpP[4];
#pragma unroll
            for (int r = 0; r < 4; r++) {
                const int e2  = wv * 16 + q * 4 + r;
                const int EiE = base + e2;
                const bool v2 = (EiE < E);
                float z = 0.f, ta = 0.f; bool on = false;
                if (sub < 7) {
                    z  = cS[r] + b2s[sub];
                    ta = v2 ? attr[(size_t)EiE * 9 + sub] : 0.f;
                    on = v2;
                } else if (sub == 7) {
                    z  = posP[e2] + posP[64 + e2] + posP[128 + e2] + posP[192 + e2] + be2s[0];
                    ta = 1.f;
                    on = v2;
                }
                const float az  = fabsf(z);
                const float L   = log1pf(expf(-az));
                const float spz = fminf(fmaxf(z, 0.f) + L, 100.f);
                const float spn = fminf(fmaxf(-z, 0.f) + L, 100.f);
                const float lossE = on ? (ta * spn + (1.f - ta) * spz) : 0.f;
                bceP[r] = lossE;
                lpP[r]  = (sub == 7) ? lossE : 0.f;
            }
#pragma unroll
            for (int o = 1; o < 16; o <<= 1)
#pragma unroll
                for (int r = 0; r < 4; r++) {
                    bceP[r] += __shfl_xor(bceP[r], o, 64);
                    lpP[r]  += __shfl_xor(lpP[r],  o, 64);
                }
            const float lossSel = (sub == 0) ? bceP[0] : (sub == 1) ? bceP[1]
                                : (sub == 2) ? bceP[2] : bceP[3];
            const float lpSel   = (sub == 0) ? lpP[0] : (sub == 1) ? lpP[1]
                                : (sub == 2) ? lpP[2] : lpP[3];
            const int eW  = wv * 16 + q * 4 + (sub & 3);
            const int EiW = base + eW;
            const bool act = (sub < 4) && (EiW < E);
            const int g = ebatch[EiW < E ? EiW : E - 1];
            seg_atomic(posSum, g, lossSel, act);
            seg_atomic(posCnt, g, 1.f, act);
            lpAcc += act ? lpSel : 0.f;
        }
    }
    if (wv < 4) wave_add(tot1, lpAcc);
}

__device__ __forceinline__ void neg_body(float* smem, int brank,
    const float* __restrict__ x, const int* __restrict__ ei, const int* __restrict__ ebatch,
    const float* __restrict__ We1, const float* __restrict__ be1,
    const float* __restrict__ We2, const float* __restrict__ be2,
    float* __restrict__ negSum, float* __restrict__ negCnt, float* __restrict__ tot2,
    int E, int ntiles)
{
    unsigned short* As16 = (unsigned short*)smem;
    float* negP = smem + 4096;           // [8][64]
    float* be1s = smem + 18048;
    float* We2s = smem + 18176;
    float* be2s = smem + 18312;

    const int t   = (int)threadIdx.x;
    const int wv  = t >> 6;
    const int l   = t & 63;
    const int sub = l & 15;
    const int q   = l >> 4;

    bf16x8 Bh[4], Bl[4];
#pragma unroll
    for (int pass = 0; pass < 8; pass++) {
        const int p = pass >> 2, kt = pass & 3;
        __syncthreads();
        {
            const int ct = t >> 6, ln = t & 63;
            const int n  = ct * 16 + (ln & 15);
            const int kb = kt * 32 + (ln >> 4) * 8;
            float f[8];
#pragma unroll
            for (int j = 0; j < 8; j++) {
                float v = We1[(kb + j) * D + n];
                f[j] = p ? (v - (float)(__bf16)v) : v;
            }
            uint4 u;
            u.x = pk2(f[0], f[1]); u.y = pk2(f[2], f[3]);
            u.z = pk2(f[4], f[5]); u.w = pk2(f[6], f[7]);
            *(uint4*)(As16 + (ct * 64 + ln) * 8) = u;
        }
        __syncthreads();
        bf16x8 f0 = *(const bf16x8*)(As16 + (wv * 64 + l) * 8);
        if (p == 0) Bh[kt] = f0; else Bl[kt] = f0;
    }
    __syncthreads();
    if (t < 128) { be1s[t] = be1[t]; We2s[t] = We2[t]; }
    if (t == 128) be2s[0] = be2[0];
    __syncthreads();

    int roff[4];
#pragma unroll
    for (int kt = 0; kt < 4; kt++) {
        const int g2 = kt + ((q >> 1) << 2);
        roff[kt] = (q * 16 + ((sub & 8) | ((sub ^ g2) & 7))) * 8;
    }
    const int e_  = t >> 3, ks_ = t & 7;
    const int gw  = (ks_ >> 1) | ((ks_ & 1) << 2);
    const int wsl = ((e_ >> 4) * 4 + (ks_ >> 1)) * 64
                  + ((ks_ & 1) * 2) * 16 + ((e_ & 8) | ((e_ ^ gw) & 7));
    unsigned short* wp = As16 + wsl * 8;
    const int k0_ = ks_ * 16;

    float lnAcc = 0.f;

    int tile = brank;
    float4 rs0, rs1, rs2, rs3, rd0, rd1, rd2, rd3;
    int sN, dN;
    {
        const int Ei0 = tile * 64 + e_;
        const int ix  = Ei0 < E ? Ei0 : E - 1;
        const int s0 = ei[ix], d0 = ei[E + ix];
        const float4* ps = (const float4*)(x + (size_t)s0 * D + k0_);
        const float4* pd = (const float4*)(x + (size_t)d0 * D + k0_);
        rs0 = ps[0]; rs1 = ps[1]; rs2 = ps[2]; rs3 = ps[3];
        rd0 = pd[0]; rd1 = pd[1]; rd2 = pd[2]; rd3 = pd[3];
        const int t1  = tile + NBLK;
        int Ei1 = (t1 < ntiles) ? t1 * 64 + e_ : 0;
        Ei1 = Ei1 < E ? Ei1 : E - 1;               // clamp
        sN = ei[Ei1]; dN = ei[E + Ei1];
    }

    for (; tile < ntiles; tile += NBLK) {
        const int base = tile * 64;
        const int Ei = base + e_;
        const bool vE = (Ei < E);
        uint4 u0, u1;
        if (vE) {
            u0.x = pk2(fmaxf(rs0.x * rd0.x, 0.f), fmaxf(rs0.y * rd0.y, 0.f));
            u0.y = pk2(fmaxf(rs0.z * rd0.z, 0.f), fmaxf(rs0.w * rd0.w, 0.f));
            u0.z = pk2(fmaxf(rs1.x * rd1.x, 0.f), fmaxf(rs1.y * rd1.y, 0.f));
            u0.w = pk2(fmaxf(rs1.z * rd1.z, 0.f), fmaxf(rs1.w * rd1.w, 0.f));
            u1.x = pk2(fmaxf(rs2.x * rd2.x, 0.f), fmaxf(rs2.y * rd2.y, 0.f));
            u1.y = pk2(fmaxf(rs2.z * rd2.z, 0.f), fmaxf(rs2.w * rd2.w, 0.f));
            u1.z = pk2(fmaxf(rs3.x * rd3.x, 0.f), fmaxf(rs3.y * rd3.y, 0.f));
            u1.w = pk2(fmaxf(rs3.z * rd3.z, 0.f), fmaxf(rs3.w * rd3.w, 0.f));
        } else { u0.x = u0.y = u0.z = u0.w = 0u; u1 = u0; }
        *(uint4*)wp = u0;
        *(uint4*)(wp + 128) = u1;
        const int t1 = tile + NBLK;
        if (t1 < ntiles) {
            const float4* ps = (const float4*)(x + (size_t)sN * D + k0_);
            const float4* pd = (const float4*)(x + (size_t)dN * D + k0_);
            rs0 = ps[0]; rs1 = ps[1]; rs2 = ps[2]; rs3 = ps[3];
            rd0 = pd[0]; rd1 = pd[1]; rd2 = pd[2]; rd3 = pd[3];
            const int t2 = t1 + NBLK;
            if (t2 < ntiles) {
                int Ei2 = t2 * 64 + e_;
                Ei2 = Ei2 < E ? Ei2 : E - 1;       // clamp
                sN = ei[Ei2]; dN = ei[E + Ei2];
            }
        }
        bar_lds();
        const int j = wv * 16 + sub;
        const float bb = be1s[j], ww = We2s[j];
#pragma unroll
        for (int mt = 0; mt < 4; mt++) {
            const int ab = mt * 2048;
            bf16x8 a0 = *(const bf16x8*)(As16 + ab +        roff[0]);
            bf16x8 a1 = *(const bf16x8*)(As16 + ab +  512 + roff[1]);
            bf16x8 a2 = *(const bf16x8*)(As16 + ab + 1024 + roff[2]);
            bf16x8 a3 = *(const bf16x8*)(As16 + ab + 1536 + roff[3]);
            f32x4 c = {0.f, 0.f, 0.f, 0.f};
            c = MFMA(a0, Bh[0], c, 0, 0, 0);
            c = MFMA(a1, Bh[1], c, 0, 0, 0);
            c = MFMA(a2, Bh[2], c, 0, 0, 0);
            c = MFMA(a3, Bh[3], c, 0, 0, 0);
            c = MFMA(a0, Bl[0], c, 0, 0, 0);
            c = MFMA(a1, Bl[1], c, 0, 0, 0);
            c = MFMA(a2, Bl[2], c, 0, 0, 0);
            c = MFMA(a3, Bl[3], c, 0, 0, 0);
            float zp0 = fmaxf(c[0] + bb, 0.f) * ww;
            float zp1 = fmaxf(c[1] + bb, 0.f) * ww;
            float zp2 = fmaxf(c[2] + bb, 0.f) * ww;
            float zp3 = fmaxf(c[3] + bb, 0.f) * ww;
#pragma unroll
            for (int o = 1; o < 16; o <<= 1) {
                zp0 += __shfl_xor(zp0, o, 64);
                zp1 += __shfl_xor(zp1, o, 64);
                zp2 += __shfl_xor(zp2, o, 64);
                zp3 += __shfl_xor(zp3, o, 64);
            }
            if (sub < 4) {
                float vv = (sub == 0) ? zp0 : (sub == 1) ? zp1 : (sub == 2) ? zp2 : zp3;
                negP[(wv << 6) + (mt << 4) + (q << 2) + sub] = vv;
            }
        }
        bar_lds();
        if (wv == 0) {
            const int EiL = base + l;
            const bool valid = (EiL < E);
            float zp = be2s[0];
#pragma unroll
            for (int i = 0; i < 8; i++) zp += negP[i * 64 + l];
            float lossN = 0.f;
            if (valid) {
                const float az = fabsf(zp);
                const float L  = log1pf(expf(-az));
                lossN = fminf(fmaxf(zp, 0.f) + L, 100.f);   // min(sp(z),100)
            }
            const int g = ebatch[EiL < E ? EiL : E - 1];
            seg_atomic(negSum, g, lossN, valid);
            seg_atomic(negCnt, g, 1.f, valid);
            lnAcc += valid ? lossN : 0.f;
        }
    }
    if (wv == 0) wave_add(tot2, lnAcc);
}

__device__ __forceinline__ void kl_body(int brank,
    const float* __restrict__ xm, const float* __restrict__ xs,
    const int* __restrict__ batch,
    float* __restrict__ klSum, float* __restrict__ klCnt, int N)
{
    const int t  = (int)threadIdx.x;
    const int wv = t >> 6, l = t & 63;
    const int hf = l >> 5, li = l & 31;      // 2 rows / wave, 32 lanes each
    const int gwv = brank * 8 + wv;
    for (int rb = gwv * 2; rb < N; rb += NBLK * 16) {
        const int row = rb + hf;
        const bool v = (row < N);
        const int rr = v ? row : (N - 1);
        const float4 mm = *(const float4*)(xm + (size_t)rr * D + li * 4);
        const float4 ss = *(const float4*)(xs + (size_t)rr * D + li * 4);
        float a;
        a  = 1.f + 2.f * fmaxf(logf(ss.x), -1e4f) - mm.x * mm.x - ss.x * ss.x;
        a += 1.f + 2.f * fmaxf(logf(ss.y), -1e4f) - mm.y * mm.y - ss.y * ss.y;
        a += 1.f + 2.f * fmaxf(logf(ss.z), -1e4f) - mm.z * mm.z - ss.z * ss.z;
        a += 1.f + 2.f * fmaxf(logf(ss.w), -1e4f) - mm.w * mm.w - ss.w * ss.w;
#pragma unroll
        for (int o = 1; o < 32; o <<= 1) a += __shfl_xor(a, o, 64);
        if (li == 0 && v) {
            const int g = batch[row];
            atomicAdd(klSum + g, -0.5f * a);
            atomicAdd(klCnt + g, 1.f);
        }
    }
}

__global__ __launch_bounds__(512, 4)
void fused_kernel(const float* __restrict__ x, const float* __restrict__ attr,
                  const float* __restrict__ xm, const float* __restrict__ xs,
                  const float* __restrict__ W1, const float* __restrict__ b1,
                  const float* __restrict__ W2, const float* __restrict__ b2,
                  const float* __restrict__ We1, const float* __restrict__ be1,
                  const float* __restrict__ We2, const float* __restrict__ be2,
                  const int* __restrict__ ei, const int* __restrict__ ein,
                  const int* __restrict__ eib, const int* __restrict__ einb,
                  const int* __restrict__ batch,
                  float* __restrict__ ws, int E, int N, int ntiles)
{
    __shared__ float smem[SMEM_F];
    const int bid   = (int)blockIdx.x;
    const int btype = bid % 3;
    const int brank = bid / 3;
    float* posSum = ws;
    float* negSum = ws + NG;
    float* klSum  = ws + 2 * NG;
    float* posCnt = ws + 3 * NG;
    float* negCnt = ws + 4 * NG;
    float* klCnt  = ws + 5 * NG;
    float* tot    = ws + 6 * NG;
    if (btype == 0)
        pos_body(smem, brank, x, ei, eib, W1, b1, W2, b2, We1, be1, We2, be2,
                 attr, posSum, posCnt, tot + 1, E, ntiles);
    else if (btype == 1)
        neg_body(smem, brank, x, ein, einb, We1, be1, We2, be2,
                 negSum, negCnt, tot + 2, E, ntiles);
    else
        kl_body(brank, xm, xs, batch, klSum, klCnt, N);
}

__global__ __launch_bounds__(256)
void final_kernel(float* __restrict__ ws) {
    const int g = (int)(blockIdx.x * blockDim.x + threadIdx.x);
    float lg = 0.f;
    if (g < NG) {
        const float cP = fmaxf(ws[3 * NG + g], 1.f);
        const float cN = fmaxf(ws[4 * NG + g], 1.f);
        const float cB = fmaxf(ws[5 * NG + g], 1.f);
        lg = ws[g] / cP + ws[NG + g] / cN + ws[2 * NG + g] / (cB * cB);
    }
#pragma unroll
    for (int o = 1; o < 64; o <<= 1) lg += __shfl_xor(lg, o, 64);
    if ((threadIdx.x & 63u) == 0) atomicAdd(ws + 6 * NG, lg);
}

__global__ void out_kernel(const float* __restrict__ ws, float* __restrict__ out, int E) {
    if (threadIdx.x == 0 && blockIdx.x == 0) {
        out[0] = ws[6 * NG] / (float)NG;
        out[1] = 0.5f * (ws[6 * NG + 1] / (float)E + ws[6 * NG + 2] / (float)E);
    }
}

extern "C" void kernel_launch(void* const* d_in, const int* in_sizes, int n_in,
                              void* d_out, int out_size, void* d_ws, size_t ws_size,
                              hipStream_t stream) {
    const float* x    = (const float*)d_in[0];
    const float* attr = (const float*)d_in[1];
    const float* xm   = (const float*)d_in[2];
    const float* xsd  = (const float*)d_in[3];
    const float* W1   = (const float*)d_in[4];
    const float* b1   = (const float*)d_in[5];
    const float* W2   = (const float*)d_in[6];
    const float* b2   = (const float*)d_in[7];
    const float* We1  = (const float*)d_in[8];
    const float* be1  = (const float*)d_in[9];
    const float* We2  = (const float*)d_in[10];
    const float* be2  = (const float*)d_in[11];
    const int* ei     = (const int*)d_in[12];
    const int* ein    = (const int*)d_in[13];
    const int* eib    = (const int*)d_in[14];
    const int* einb   = (const int*)d_in[15];
    const int* batch  = (const int*)d_in[16];

    const int N = in_sizes[0] / D;       // 100000
    const int E = in_sizes[14];          // 600000

    float* ws = (float*)d_ws;
    hipMemsetAsync(d_ws, 0, (size_t)(6 * NG + 4) * sizeof(float), stream);

    const int ntiles = (E + 63) / 64;
    fused_kernel<<<3 * NBLK, 512, 0, stream>>>(x, attr, xm, xsd,
                                               W1, b1, W2, b2, We1, be1, We2, be2,
                                               ei, ein, eib, einb, batch,
                                               ws, E, N, ntiles);
    final_kernel<<<(NG + 255) / 256, 256, 0, stream>>>(ws);
    out_kernel<<<1, 64, 0, stream>>>(ws, (float*)d_out, E);
}